// Round 11
// baseline (575.881 us; speedup 1.0000x reference)
//
#include <hip/hip_runtime.h>
#include <hip/hip_bf16.h>
#include <math.h>

using short8 = __attribute__((ext_vector_type(8))) short;
using f32x16 = __attribute__((ext_vector_type(16))) float;
using f32x2  = __attribute__((ext_vector_type(2))) float;

constexpr int B  = 1024;
constexpr int NN = 128;   // nodes per tree
constexpr int F  = 318;   // raw features

__device__ inline float bf2f(unsigned short u) {
    union { unsigned int i; float f; } x; x.i = ((unsigned int)u) << 16; return x.f;
}
__device__ inline unsigned short f2bf(float f) {
    union { float f; unsigned int i; } x; x.f = f;
    unsigned int r = x.i + 0x7fff + ((x.i >> 16) & 1);
    return (unsigned short)(r >> 16);
}

// ---------- encoder prepack: 32x32x16 B-frag order ----------
__global__ __launch_bounds__(256) void prepack_w32(const float* __restrict__ w,
                                                   unsigned short* __restrict__ wp,
                                                   int kmul, int OREAL, int CREAL,
                                                   int CC, int COUT, int KS, int NCC, int KTOT)
{
    int t = blockIdx.x * 256 + threadIdx.x;
    if (t >= KTOT * COUT) return;
    int j = t & 7;
    int lane = (t >> 3) & 63;
    int rest = t >> 9;
    int obn = COUT / 32;
    int ob = rest % obn;
    int kbg = rest / obn;
    int ks = kbg % KS;
    int t2 = kbg / KS;
    int cc = t2 % NCC;
    int k  = t2 / NCC;
    int c = cc * CC + ks * 16 + (lane >> 5) * 8 + j;
    int o = ob * 32 + (lane & 31);
    float v = 0.f;
    if (c < CREAL && o < OREAL)
        v = (kmul == 3) ? w[((size_t)o * CREAL + c) * 3 + k] : w[(size_t)o * CREAL + c];
    wp[t] = f2bf(v);
}

// ---------- conv prepack: chunk-contiguous [oy][ci][k][ks][cb][lane][j], CC=32, KS=2, OT=128 ----------
__global__ __launch_bounds__(256) void prepack_wB(const float* __restrict__ w,
                                                  unsigned short* __restrict__ wp,
                                                  int OREAL, int CREAL, int CIN, int COUT)
{
    const int NCC = CIN / 32;
    int t = blockIdx.x * 256 + threadIdx.x;
    if (t >= 3 * CIN * ((COUT + 127) & ~127)) return;
    int j = t & 7;
    int lane = (t >> 3) & 63;
    int r = t >> 9;
    int cb = r & 3; r >>= 2;
    int ks = r & 1; r >>= 1;
    int k = r % 3; r /= 3;
    int ci = r % NCC;
    int oy = r / NCC;
    int c = ci * 32 + ks * 16 + (lane >> 5) * 8 + j;
    int o = oy * 128 + cb * 32 + (lane & 31);
    float v = 0.f;
    if (c < CREAL && o < OREAL) v = w[((size_t)o * CREAL + c) * 3 + k];
    wp[t] = f2bf(v);
}

// ---------- encoder, fused transpose: trees [B][F][NN] f32 -> x0 [B][NN][128] bf16 ----------
__global__ __launch_bounds__(256, 2) void enc_fused(const float* __restrict__ trees,
                                                    const unsigned short* __restrict__ wp,
                                                    const float* __restrict__ bias,
                                                    unsigned short* __restrict__ x0)
{
    constexpr int CC = 64, NCH = 5, KS = 4, NB = 4, OT = 128;
    constexpr int BUFB = NN * CC * 2;       // 16 KB
    __shared__ __align__(16) char gbuf[2 * BUFB];

    const int b = blockIdx.x;
    const int tid = threadIdx.x;
    const int lane = tid & 63;
    const int wm = tid >> 6;
    const int l31 = lane & 31, lh2 = lane >> 5;

    const int cl = tid >> 2;
    const int nq = tid & 3;

    float4 vv[8];
    auto load = [&](int ch) {
        const int c = ch * CC + cl;
        const bool ok = (c < F);
        const float* src = trees + ((size_t)b * F + c) * NN + nq * 32;
#pragma unroll
        for (int j = 0; j < 8; ++j)
            vv[j] = ok ? *reinterpret_cast<const float4*>(src + j * 4) : make_float4(0.f, 0.f, 0.f, 0.f);
    };
    const int gsw = cl >> 3, cby = (cl & 7) * 2;
    auto stor = [&](char* wb) {
#pragma unroll
        for (int j = 0; j < 8; ++j) {
            const int n0 = nq * 32 + j * 4;
            const float f4[4] = {vv[j].x, vv[j].y, vv[j].z, vv[j].w};
#pragma unroll
            for (int r = 0; r < 4; ++r) {
                const int n = n0 + r;
                *reinterpret_cast<unsigned short*>(
                    wb + n * (CC * 2) + (((gsw ^ (n & 7)) << 4) + cby)) = f2bf(f4[r]);
            }
        }
    };

    f32x16 acc[NB];
#pragma unroll
    for (int ob = 0; ob < NB; ++ob) acc[ob] = (f32x16)0.f;

    const int nrow = wm * 32 + l31;
    const unsigned abyte = (unsigned)(nrow * (CC * 2));
    const unsigned axor = (unsigned)((nrow & 7) << 4);

    load(0); stor(gbuf);
    __syncthreads();

    int p = 0;
#pragma unroll
    for (int ch = 0; ch < NCH; ++ch) {
        if (ch + 1 < NCH) load(ch + 1);
        const char* base = gbuf + p * BUFB;
        __builtin_amdgcn_s_setprio(1);
#pragma unroll
        for (int ks = 0; ks < KS; ++ks) {
            const int kbg = ch * KS + ks;
            short8 a = *reinterpret_cast<const short8*>(
                base + abyte + (((unsigned)((ks * 2 + lh2) << 4)) ^ axor));
            const unsigned short* wb_ = wp + ((size_t)(kbg * 4) * 64 + lane) * 8;
#pragma unroll
            for (int ob = 0; ob < NB; ++ob) {
                short8 bf_ = *reinterpret_cast<const short8*>(wb_ + ob * 512);
                acc[ob] = __builtin_amdgcn_mfma_f32_32x32x16_bf16(a, bf_, acc[ob], 0, 0, 0);
            }
        }
        __builtin_amdgcn_s_setprio(0);
        if (ch + 1 < NCH) stor(gbuf + (p ^ 1) * BUFB);
        __syncthreads();
        p ^= 1;
    }

    unsigned short* xs = reinterpret_cast<unsigned short*>(gbuf);
    float bs[NB];
#pragma unroll
    for (int ob = 0; ob < NB; ++ob) {
        int o = ob * 32 + l31;
        bs[ob] = (o < 109) ? bias[o] : 0.f;
    }
#pragma unroll
    for (int ob = 0; ob < NB; ++ob)
#pragma unroll
        for (int r = 0; r < 16; ++r) {
            float val = acc[ob][r] + bs[ob];
            int row = wm * 32 + (r & 3) + 8 * (r >> 2) + 4 * lh2;
            xs[row * OT + ob * 32 + l31] = f2bf(val);
        }
    __syncthreads();
#pragma unroll
    for (int i = 0; i < 8; ++i) {
        int e = i * 256 + tid;
        int n = e >> 4, g = e & 15;
        *reinterpret_cast<uint4*>(x0 + ((size_t)b * NN + n) * 128 + g * 8)
            = *reinterpret_cast<const uint4*>(xs + n * OT + g * 8);
    }
}

// ---------- tree conv: DENSE GEMM, nf=4 wave tile (128r x 32c), CC=32, padded-128B A rows ----------
// Z_k = T(x) @ W_k^T dense; y[n][o] = bias[o] + sum_k Z_k[idx[3n+k]][o]
template <int CIN, int OTN, int COUT, bool NORM, bool COLMAX>
__global__ __launch_bounds__(256, 2) void conv_gemm(const unsigned short* __restrict__ xin, // [B][NN][CIN]
                                                    const int* __restrict__ idx,            // [B][3*NN]
                                                    const unsigned short* __restrict__ wp,  // [oy][ci][k][ks][cb] frags
                                                    const float* __restrict__ bias,
                                                    const float* __restrict__ stats,
                                                    unsigned short* __restrict__ yout,      // [B][NN][COUT]
                                                    float* __restrict__ colmax,             // [B][COUT]
                                                    float* __restrict__ partials)
{
    constexpr int CC    = 32;
    constexpr int NCC   = CIN / CC;
    constexpr int KS    = 2;
    constexpr int AIT   = 2;                  // A granules/thread (128 rows * 4 gr / 256 thr)
    constexpr int ABUF  = NN * 128;           // 16 KB (padded 128B rows)
    constexpr int BFR   = KS * 3 * 4;         // 24 frags (ks x k x colblock)
    constexpr int BBUF  = BFR * 1024;         // 24 KB
    constexpr int BIT   = BBUF / 4096;        // 6 B-granules/thread
    constexpr int BUFB  = ABUF + BBUF;        // 40 KB
    constexpr int SMEM  = 2 * BUFB;           // 80 KB (Z, rbuf, cmax alias inside)

    __shared__ __align__(16) char gbuf[SMEM];
    float (*cmax)[2][16] = reinterpret_cast<float (*)[2][16]>(gbuf + 49664); // 512 B
    float* rbuf = reinterpret_cast<float*>(gbuf + 50432);                    // 32 B

    // XCD-grouping decode
    const int f  = blockIdx.x;
    const int s  = f >> 3;
    const int b  = (f & 7) + 8 * (s / OTN);
    const int oy = s % OTN;                   // o-tile base = oy*128

    const int tid = threadIdx.x;
    const int lane = tid & 63;
    const int wv = tid >> 6;                  // wave = col-block cb
    const int l31 = lane & 31, lh2 = lane >> 5;

    float inv = 1.f, nmi = 0.f;
    if (NORM) { float mu = stats[0]; inv = stats[1]; nmi = -mu * inv; }

    const unsigned short* xb = xin + (size_t)b * NN * CIN;

    // epilogue gather rows
    const int en = tid >> 1, eh = tid & 1;
    int sk[3];
#pragma unroll
    for (int k = 0; k < 3; ++k) sk[k] = idx[b * 3 * NN + 3 * en + k];

    f32x16 acc[4][3];
#pragma unroll
    for (int nf = 0; nf < 4; ++nf)
#pragma unroll
        for (int k = 0; k < 3; ++k) acc[nf][k] = (f32x16)0.f;

    // ---- staging ----
    auto issueB = [&](int ci, char* dst) {
        const unsigned short* src = wp + ((size_t)(oy * NCC + ci)) * (BFR * 512);
#pragma unroll
        for (int i = 0; i < BIT; ++i)
            __builtin_amdgcn_global_load_lds(
                (const __attribute__((address_space(1))) void*)(src + (i * 256 + tid) * 8),
                (__attribute__((address_space(3))) void*)(dst + (i * 256 + wv * 64) * 16),
                16, 0, 0);
    };
    uint4 v[AIT];
    unsigned ngoff[AIT], lby[AIT];
#pragma unroll
    for (int i = 0; i < AIT; ++i) {
        int it = i * 256 + tid;
        int n = it >> 2, g = it & 3;
        ngoff[i] = (unsigned)(n * CIN + g * 8);
        lby[i]   = (unsigned)(n * 128 + ((g ^ (n & 7)) << 4));
    }
    auto loadA = [&](int cc) {
#pragma unroll
        for (int i = 0; i < AIT; ++i)
            v[i] = *reinterpret_cast<const uint4*>(xb + cc * CC + ngoff[i]);
    };
    const f32x2 iv2 = {inv, inv}, nm2 = {nmi, nmi};
    auto storA = [&](char* wb) {
#pragma unroll
        for (int i = 0; i < AIT; ++i) {
            uint4 t = v[i];
            if (NORM) {
                unsigned int* pw = reinterpret_cast<unsigned int*>(&t);
#pragma unroll
                for (int q = 0; q < 4; ++q) {
                    unsigned int u = pw[q];
                    f32x2 sv, d;
                    sv[0] = __uint_as_float(u << 16);
                    sv[1] = __uint_as_float(u & 0xffff0000u);
                    asm("v_pk_fma_f32 %0, %1, %2, %3" : "=v"(d) : "v"(sv), "v"(iv2), "v"(nm2));
                    float f0 = fmaxf(d[0], 0.f);
                    float f1 = fmaxf(d[1], 0.f);
                    unsigned int r;
                    asm("v_cvt_pk_bf16_f32 %0, %1, %2" : "=v"(r) : "v"(f0), "v"(f1));
                    pw[q] = r;
                }
            }
            *reinterpret_cast<uint4*>(wb + lby[i]) = t;
        }
    };

    // A-read bases: abase = n*128 | ((n&7)<<4); addr = abase ^ (slot<<4), slot = ks*2+lh2
    unsigned abase[4];
#pragma unroll
    for (int nf = 0; nf < 4; ++nf) {
        int n = nf * 32 + l31;
        abase[nf] = (unsigned)(n * 128 + ((n & 7) << 4));
    }

    // prologue: stage chunk 0
    issueB(0, gbuf + ABUF);
    loadA(0); storA(gbuf);
    __syncthreads();

    int p = 0;
    for (int cc = 0; cc < NCC; ++cc) {
        if (cc + 1 < NCC) {
            issueB(cc + 1, gbuf + (p ^ 1) * BUFB + ABUF);
            loadA(cc + 1);
        }
        const char* ab = gbuf + p * BUFB;
        const char* bb = ab + ABUF;
        __builtin_amdgcn_s_setprio(1);
#pragma unroll
        for (int ks = 0; ks < KS; ++ks) {
            const unsigned sx = (unsigned)((ks * 2 + lh2) << 4);
            short8 a0 = *reinterpret_cast<const short8*>(ab + (abase[0] ^ sx));
            short8 a1 = *reinterpret_cast<const short8*>(ab + (abase[1] ^ sx));
            short8 a2 = *reinterpret_cast<const short8*>(ab + (abase[2] ^ sx));
            short8 a3 = *reinterpret_cast<const short8*>(ab + (abase[3] ^ sx));
#pragma unroll
            for (int k = 0; k < 3; ++k) {
                short8 bf_ = *reinterpret_cast<const short8*>(
                    bb + (((k * KS + ks) * 4 + wv) << 10) + lane * 16);
                acc[0][k] = __builtin_amdgcn_mfma_f32_32x32x16_bf16(a0, bf_, acc[0][k], 0, 0, 0);
                acc[1][k] = __builtin_amdgcn_mfma_f32_32x32x16_bf16(a1, bf_, acc[1][k], 0, 0, 0);
                acc[2][k] = __builtin_amdgcn_mfma_f32_32x32x16_bf16(a2, bf_, acc[2][k], 0, 0, 0);
                acc[3][k] = __builtin_amdgcn_mfma_f32_32x32x16_bf16(a3, bf_, acc[3][k], 0, 0, 0);
            }
        }
        __builtin_amdgcn_s_setprio(0);
        if (cc + 1 < NCC) storA(gbuf + (p ^ 1) * BUFB);
        __syncthreads();
        p ^= 1;
    }

    // ---------------- epilogue: 4 col-rounds; Z (f32, 48KB) -> output-side gather ----------------
    float* Z = reinterpret_cast<float*>(gbuf);
    float tsum = 0.f, tss = 0.f;
#pragma unroll
    for (int cb = 0; cb < 4; ++cb) {
        __syncthreads();
        if (wv == cb) {
#pragma unroll
            for (int k = 0; k < 3; ++k)
#pragma unroll
                for (int nf = 0; nf < 4; ++nf)
#pragma unroll
                    for (int r = 0; r < 16; ++r) {
                        int row = nf * 32 + (r & 3) + 8 * (r >> 2) + 4 * lh2;
                        Z[(k * NN + row) * 32 + (l31 ^ ((row & 7) << 2))] = acc[nf][k][r];
                    }
        }
        __syncthreads();

        float val[16];
        {
            const float* bp = bias + oy * 128 + cb * 32 + eh * 16;
#pragma unroll
            for (int j = 0; j < 16; ++j) val[j] = bp[j];
        }
#pragma unroll
        for (int k = 0; k < 3; ++k) {
            const float* zr = Z + (k * NN + sk[k]) * 32;
            const int sw = sk[k] & 7;
#pragma unroll
            for (int q4 = 0; q4 < 4; ++q4) {
                const int q = eh * 4 + q4;
                float4 z = *reinterpret_cast<const float4*>(zr + ((q ^ sw) << 2));
                val[q4 * 4 + 0] += z.x;
                val[q4 * 4 + 1] += z.y;
                val[q4 * 4 + 2] += z.z;
                val[q4 * 4 + 3] += z.w;
            }
        }
#pragma unroll
        for (int j = 0; j < 16; ++j) { tsum += val[j]; tss += val[j] * val[j]; }

        if (COLMAX) {
#pragma unroll
            for (int m = 2; m <= 32; m <<= 1)
#pragma unroll
                for (int j = 0; j < 16; ++j) val[j] = fmaxf(val[j], __shfl_xor(val[j], m));
            if ((lane >> 1) == 0) {
#pragma unroll
                for (int j = 0; j < 16; ++j) cmax[wv][lane & 1][j] = val[j];
            }
            __syncthreads();
            if (tid < 32) {
                float m = fmaxf(fmaxf(cmax[0][tid >> 4][tid & 15], cmax[1][tid >> 4][tid & 15]),
                                fmaxf(cmax[2][tid >> 4][tid & 15], cmax[3][tid >> 4][tid & 15]));
                colmax[b * COUT + oy * 128 + cb * 32 + (tid >> 4) * 16 + (tid & 15)] = m;
            }
        } else {
            unsigned int pk[8];
#pragma unroll
            for (int j = 0; j < 8; ++j)
                asm("v_cvt_pk_bf16_f32 %0, %1, %2" : "=v"(pk[j]) : "v"(val[2 * j]), "v"(val[2 * j + 1]));
            unsigned short* dst = yout + ((size_t)b * NN + en) * COUT + oy * 128 + cb * 32 + eh * 16;
            reinterpret_cast<uint4*>(dst)[0] = make_uint4(pk[0], pk[1], pk[2], pk[3]);
            reinterpret_cast<uint4*>(dst)[1] = make_uint4(pk[4], pk[5], pk[6], pk[7]);
        }
    }

    // block stats reduction
#pragma unroll
    for (int ss = 32; ss; ss >>= 1) { tsum += __shfl_down(tsum, ss); tss += __shfl_down(tss, ss); }
    if (lane == 0) { rbuf[wv * 2] = tsum; rbuf[wv * 2 + 1] = tss; }
    __syncthreads();
    if (tid == 0) {
        float sm = rbuf[0] + rbuf[2] + rbuf[4] + rbuf[6];
        float q = rbuf[1] + rbuf[3] + rbuf[5] + rbuf[7];
        int gid = oy * B + b;
        partials[2 * gid] = sm;
        partials[2 * gid + 1] = q;
    }
}

// ---------- finalize global layernorm stats ----------
__global__ __launch_bounds__(256) void stats_kernel(const float* __restrict__ partials,
                                                    float* __restrict__ stats,
                                                    int npart, double ntot)
{
    __shared__ double sd[256], sd2[256];
    double s = 0.0, s2 = 0.0;
    for (int i = threadIdx.x; i < npart; i += 256) { s += (double)partials[2 * i]; s2 += (double)partials[2 * i + 1]; }
    sd[threadIdx.x] = s; sd2[threadIdx.x] = s2;
    __syncthreads();
    for (int k = 128; k > 0; k >>= 1) {
        if (threadIdx.x < k) { sd[threadIdx.x] += sd[threadIdx.x + k]; sd2[threadIdx.x] += sd2[threadIdx.x + k]; }
        __syncthreads();
    }
    if (threadIdx.x == 0) {
        double mu = sd[0] / ntot;
        double var = (sd2[0] - sd[0] * sd[0] / ntot) / (ntot - 1.0);
        double sdv = sqrt(var > 0.0 ? var : 0.0);
        stats[0] = (float)mu;
        stats[1] = (float)(1.0 / (sdv + 1e-5));
    }
}

// ---------- heads from per-column max (raw) ----------
__global__ __launch_bounds__(128) void pool_head_kernel(const float* __restrict__ colmax,  // [B][128]
                                                        const float* __restrict__ stats,
                                                        const float* __restrict__ latw,
                                                        const float* __restrict__ latb,
                                                        const float* __restrict__ costw,
                                                        const float* __restrict__ costb,
                                                        float* __restrict__ out)
{
    const int b = blockIdx.x, t = threadIdx.x;
    const float mu = stats[0], inv = stats[1];
    const float pooled = fmaxf((colmax[b * 128 + t] - mu) * inv, 0.f);
    __shared__ float pl[128];
    pl[t] = pooled;
    __syncthreads();
    const float* w = (t < 64) ? latw : costw;
    const int l = t & 63;
    float v = pl[l] * w[l] + pl[l + 64] * w[l + 64];
#pragma unroll
    for (int s = 32; s > 0; s >>= 1) v += __shfl_down(v, s);
    if (l == 0) {
        const float bb = (t < 64) ? latb[0] : costb[0];
        out[(t < 64 ? 0 : B) + b] = 1.f / (1.f + expf(-(v + bb)));
    }
}

// ---------- launch ----------
extern "C" void kernel_launch(void* const* d_in, const int* in_sizes, int n_in,
                              void* d_out, int out_size, void* d_ws, size_t ws_size,
                              hipStream_t stream)
{
    (void)in_sizes; (void)n_in; (void)out_size; (void)ws_size;
    const float* trees   = (const float*)d_in[0];
    const int*   indexes = (const int*)  d_in[1];
    const float* enc_w   = (const float*)d_in[2];
    const float* enc_b   = (const float*)d_in[3];
    const float* w1 = (const float*)d_in[4];
    const float* b1 = (const float*)d_in[5];
    const float* w2 = (const float*)d_in[6];
    const float* b2 = (const float*)d_in[7];
    const float* w3 = (const float*)d_in[8];
    const float* b3 = (const float*)d_in[9];
    const float* lat_w  = (const float*)d_in[10];
    const float* lat_b  = (const float*)d_in[11];
    const float* cost_w = (const float*)d_in[12];
    const float* cost_b = (const float*)d_in[13];
    float* out = (float*)d_out;

    char* ws = (char*)d_ws;
    size_t off = 0;
    auto alloc = [&](size_t bytes) -> char* {
        char* p = ws + off;
        off += (bytes + 255) & ~(size_t)255;
        return p;
    };
    unsigned short* wpe = (unsigned short*)alloc((size_t)320 * 128 * 2);
    unsigned short* wp1 = (unsigned short*)alloc((size_t)3 * 128 * 512 * 2);
    unsigned short* wp2 = (unsigned short*)alloc((size_t)3 * 512 * 256 * 2);
    unsigned short* wp3 = (unsigned short*)alloc((size_t)3 * 256 * 128 * 2);
    unsigned short* x0  = (unsigned short*)alloc((size_t)B * NN * 128 * 2);
    unsigned short* y1  = (unsigned short*)alloc((size_t)B * NN * 512 * 2);
    unsigned short* y2  = (unsigned short*)alloc((size_t)B * NN * 256 * 2);
    float* colmax   = (float*)alloc((size_t)B * 128 * 4);
    float* partials = (float*)alloc((size_t)8192 * 2 * 4);
    float* stats    = (float*)alloc(8 * 4);

    prepack_w32<<<dim3((320 * 128 + 255) / 256), dim3(256), 0, stream>>>(enc_w, wpe, 1, 109, 318, 64, 128, 4, 5, 320);
    prepack_wB<<<dim3((3 * 128 * 512) / 256), dim3(256), 0, stream>>>(w1, wp1, 512, 109, 128, 512);
    prepack_wB<<<dim3((3 * 512 * 256) / 256), dim3(256), 0, stream>>>(w2, wp2, 256, 512, 512, 256);
    prepack_wB<<<dim3((3 * 256 * 128) / 256), dim3(256), 0, stream>>>(w3, wp3, 128, 256, 256, 128);

    // encoder (fused transpose): trees -> x0 [B][NN][128]
    enc_fused<<<dim3(B), dim3(256), 0, stream>>>(trees, wpe, enc_b, x0);

    // conv1: OT=128 x 4 o-tiles
    conv_gemm<128, 4, 512, false, false>
        <<<dim3(B * 4), dim3(256), 0, stream>>>(x0, indexes, wp1, b1, stats, y1, colmax, partials);
    stats_kernel<<<dim3(1), dim3(256), 0, stream>>>(partials, stats + 0, 4096, (double)((size_t)B * 512 * NN));

    // conv2: OT=128 x 2 o-tiles
    conv_gemm<512, 2, 256, true, false>
        <<<dim3(B * 2), dim3(256), 0, stream>>>(y1, indexes, wp2, b2, stats + 0, y2, colmax, partials);
    stats_kernel<<<dim3(1), dim3(256), 0, stream>>>(partials, stats + 2, 2048, (double)((size_t)B * 256 * NN));

    // conv3: OT=128, colmax fused
    conv_gemm<256, 1, 128, true, true>
        <<<dim3(B), dim3(256), 0, stream>>>(y2, indexes, wp3, b3, stats + 2, nullptr, colmax, partials);
    stats_kernel<<<dim3(1), dim3(256), 0, stream>>>(partials, stats + 4, 1024, (double)((size_t)B * 128 * NN));

    pool_head_kernel<<<dim3(B), dim3(128), 0, stream>>>(colmax, stats + 4, lat_w, lat_b, cost_w, cost_b, out);
}

// Round 12
// 406.852 us; speedup vs baseline: 1.4155x; 1.4155x over previous
//
#include <hip/hip_runtime.h>
#include <hip/hip_bf16.h>
#include <math.h>

using short8 = __attribute__((ext_vector_type(8))) short;
using f32x16 = __attribute__((ext_vector_type(16))) float;
using f32x2  = __attribute__((ext_vector_type(2))) float;

#define AS3 __attribute__((address_space(3)))

constexpr int B  = 1024;
constexpr int NN = 128;   // nodes per tree
constexpr int F  = 318;   // raw features

__device__ inline float bf2f(unsigned short u) {
    union { unsigned int i; float f; } x; x.i = ((unsigned int)u) << 16; return x.f;
}
__device__ inline unsigned short f2bf(float f) {
    union { float f; unsigned int i; } x; x.f = f;
    unsigned int r = x.i + 0x7fff + ((x.i >> 16) & 1);
    return (unsigned short)(r >> 16);
}

// ---------- encoder prepack: 32x32x16 B-frag order ----------
__global__ __launch_bounds__(256) void prepack_w32(const float* __restrict__ w,
                                                   unsigned short* __restrict__ wp,
                                                   int kmul, int OREAL, int CREAL,
                                                   int CC, int COUT, int KS, int NCC, int KTOT)
{
    int t = blockIdx.x * 256 + threadIdx.x;
    if (t >= KTOT * COUT) return;
    int j = t & 7;
    int lane = (t >> 3) & 63;
    int rest = t >> 9;
    int obn = COUT / 32;
    int ob = rest % obn;
    int kbg = rest / obn;
    int ks = kbg % KS;
    int t2 = kbg / KS;
    int cc = t2 % NCC;
    int k  = t2 / NCC;
    int c = cc * CC + ks * 16 + (lane >> 5) * 8 + j;
    int o = ob * 32 + (lane & 31);
    float v = 0.f;
    if (c < CREAL && o < OREAL)
        v = (kmul == 3) ? w[((size_t)o * CREAL + c) * 3 + k] : w[(size_t)o * CREAL + c];
    wp[t] = f2bf(v);
}

// ---------- conv prepack: chunk-contiguous [oy][ci][k][ks][obp][lane][j], CC=64, KS=4 ----------
__global__ __launch_bounds__(256) void prepack_wB(const float* __restrict__ w,
                                                  unsigned short* __restrict__ wp,
                                                  int OREAL, int CREAL, int CIN, int COUT)
{
    const int NCC = CIN / 64;
    int t = blockIdx.x * 256 + threadIdx.x;
    if (t >= 3 * CIN * COUT) return;
    int j = t & 7;
    int lane = (t >> 3) & 63;
    int r = t >> 9;
    int obp = r & 1; r >>= 1;
    int ks = r & 3; r >>= 2;
    int k = r % 3; r /= 3;
    int ci = r % NCC;
    int oy = r / NCC;
    int c = ci * 64 + ks * 16 + (lane >> 5) * 8 + j;
    int o = oy * 64 + obp * 32 + (lane & 31);
    float v = 0.f;
    if (c < CREAL && o < OREAL) v = w[((size_t)o * CREAL + c) * 3 + k];
    wp[t] = f2bf(v);
}

// ---------- encoder, fused transpose: trees [B][F][NN] f32 -> x0 [B][NN][128] bf16 ----------
__global__ __launch_bounds__(256, 2) void enc_fused(const float* __restrict__ trees,
                                                    const unsigned short* __restrict__ wp,
                                                    const float* __restrict__ bias,
                                                    unsigned short* __restrict__ x0)
{
    constexpr int CC = 64, NCH = 5, KS = 4, NB = 4, OT = 128;
    constexpr int BUFB = NN * CC * 2;       // 16 KB
    __shared__ __align__(16) char gbuf[2 * BUFB];

    const int b = blockIdx.x;
    const int tid = threadIdx.x;
    const int lane = tid & 63;
    const int wm = tid >> 6;
    const int l31 = lane & 31, lh2 = lane >> 5;

    const int cl = tid >> 2;
    const int nq = tid & 3;

    float4 vv[8];
    auto load = [&](int ch) {
        const int c = ch * CC + cl;
        const bool ok = (c < F);
        const float* src = trees + ((size_t)b * F + c) * NN + nq * 32;
#pragma unroll
        for (int j = 0; j < 8; ++j)
            vv[j] = ok ? *reinterpret_cast<const float4*>(src + j * 4) : make_float4(0.f, 0.f, 0.f, 0.f);
    };
    const int gsw = cl >> 3, cby = (cl & 7) * 2;
    auto stor = [&](char* wb) {
#pragma unroll
        for (int j = 0; j < 8; ++j) {
            const int n0 = nq * 32 + j * 4;
            const float f4[4] = {vv[j].x, vv[j].y, vv[j].z, vv[j].w};
#pragma unroll
            for (int r = 0; r < 4; ++r) {
                const int n = n0 + r;
                *reinterpret_cast<unsigned short*>(
                    wb + n * (CC * 2) + (((gsw ^ (n & 7)) << 4) + cby)) = f2bf(f4[r]);
            }
        }
    };

    f32x16 acc[NB];
#pragma unroll
    for (int ob = 0; ob < NB; ++ob) acc[ob] = (f32x16)0.f;

    const int nrow = wm * 32 + l31;
    const unsigned abyte = (unsigned)(nrow * (CC * 2));
    const unsigned axor = (unsigned)((nrow & 7) << 4);

    load(0); stor(gbuf);
    __syncthreads();

    int p = 0;
#pragma unroll
    for (int ch = 0; ch < NCH; ++ch) {
        if (ch + 1 < NCH) load(ch + 1);
        const char* base = gbuf + p * BUFB;
        __builtin_amdgcn_s_setprio(1);
#pragma unroll
        for (int ks = 0; ks < KS; ++ks) {
            const int kbg = ch * KS + ks;
            short8 a = *reinterpret_cast<const short8*>(
                base + abyte + (((unsigned)((ks * 2 + lh2) << 4)) ^ axor));
            const unsigned short* wb_ = wp + ((size_t)(kbg * 4) * 64 + lane) * 8;
#pragma unroll
            for (int ob = 0; ob < NB; ++ob) {
                short8 bf_ = *reinterpret_cast<const short8*>(wb_ + ob * 512);
                acc[ob] = __builtin_amdgcn_mfma_f32_32x32x16_bf16(a, bf_, acc[ob], 0, 0, 0);
            }
        }
        __builtin_amdgcn_s_setprio(0);
        if (ch + 1 < NCH) stor(gbuf + (p ^ 1) * BUFB);
        __syncthreads();
        p ^= 1;
    }

    unsigned short* xs = reinterpret_cast<unsigned short*>(gbuf);
    float bs[NB];
#pragma unroll
    for (int ob = 0; ob < NB; ++ob) {
        int o = ob * 32 + l31;
        bs[ob] = (o < 109) ? bias[o] : 0.f;
    }
#pragma unroll
    for (int ob = 0; ob < NB; ++ob)
#pragma unroll
        for (int r = 0; r < 16; ++r) {
            float val = acc[ob][r] + bs[ob];
            int row = wm * 32 + (r & 3) + 8 * (r >> 2) + 4 * lh2;
            xs[row * OT + ob * 32 + l31] = f2bf(val);
        }
    __syncthreads();
#pragma unroll
    for (int i = 0; i < 8; ++i) {
        int e = i * 256 + tid;
        int n = e >> 4, g = e & 15;
        *reinterpret_cast<uint4*>(x0 + ((size_t)b * NN + n) * 128 + g * 8)
            = *reinterpret_cast<const uint4*>(xs + n * OT + g * 8);
    }
}

// ---------- tree conv: DENSE GEMM, all-LDS operands, CC=64, 2-deep A prefetch ----------
// Z_k = T(x) @ W_k^T dense; y[n][o] = bias[o] + sum_k Z_k[idx[3n+k]][o]
template <int CIN, int OTN, int COUT, bool NORM, bool COLMAX, bool GLLA>
__global__ __launch_bounds__(256, 2) void conv_gemm(const unsigned short* __restrict__ xin, // [B][NN][CIN]
                                                    const int* __restrict__ idx,            // [B][3*NN]
                                                    const unsigned short* __restrict__ wp,  // [oy][ci][k][ks][obp] frags
                                                    const float* __restrict__ bias,
                                                    const float* __restrict__ stats,
                                                    unsigned short* __restrict__ yout,      // [B][NN][COUT]
                                                    float* __restrict__ colmax,             // [B][COUT]
                                                    float* __restrict__ partials)
{
    constexpr int CC    = 64;
    constexpr int NCC   = CIN / CC;
    constexpr int KS    = 4;
    constexpr int AIT   = 4;                  // A granules/thread
    constexpr int ABUF  = NN * CC * 2;        // 16 KB
    constexpr int BFR   = KS * 3 * 2;         // 24 frags
    constexpr int BBUF  = BFR * 1024;         // 24 KB
    constexpr int BIT   = BBUF / 4096;        // 6 B-granules/thread
    constexpr int BUFB  = ABUF + BBUF;        // 40 KB
    constexpr int SMEM  = 2 * BUFB;           // 80 KB (Z, rbuf, cmax alias inside)

    __shared__ __align__(16) char gbuf[SMEM];
    float* rbuf = reinterpret_cast<float*>(gbuf + 81408);          // 32 B
    float (*cmax)[2][16] = reinterpret_cast<float (*)[2][16]>(gbuf + 80640); // 512 B

    // XCD-grouping decode
    const int f  = blockIdx.x;
    const int s  = f >> 3;
    const int b  = (f & 7) + 8 * (s / OTN);
    const int oy = s % OTN;                   // o-tile base = oy*64

    const int tid = threadIdx.x;
    const int lane = tid & 63;
    const int wv = tid >> 6;
    const int wm = wv >> 1, wn = wv & 1;
    const int l31 = lane & 31, lh2 = lane >> 5;

    float inv = 1.f, nmi = 0.f;
    if (NORM) { float mu = stats[0]; inv = stats[1]; nmi = -mu * inv; }

    const unsigned short* xb = xin + (size_t)b * NN * CIN;

    // epilogue gather rows
    const int en = tid >> 1, eh = tid & 1;
    int sk[3];
#pragma unroll
    for (int k = 0; k < 3; ++k) sk[k] = idx[b * 3 * NN + 3 * en + k];

    f32x16 acc[2][3];
#pragma unroll
    for (int nf = 0; nf < 2; ++nf)
#pragma unroll
        for (int k = 0; k < 3; ++k) acc[nf][k] = (f32x16)0.f;

    // ---- staging ----
    auto issueB = [&](int ci, char* dst) {
        const unsigned short* src = wp + ((size_t)(oy * NCC + ci)) * (BFR * 512);
#pragma unroll
        for (int i = 0; i < BIT; ++i)
            __builtin_amdgcn_global_load_lds(
                (const AS3 void*)0 == (const AS3 void*)0  // keep type
                ? (const __attribute__((address_space(1))) void*)(src + (i * 256 + tid) * 8)
                : (const __attribute__((address_space(1))) void*)(src),
                (AS3 void*)(dst + (i * 256 + wv * 64) * 16),
                16, 0, 0);
    };
    auto issueA = [&](int cc, char* dst) {    // GLLA path (no transform)
#pragma unroll
        for (int i = 0; i < AIT; ++i) {
            int it = i * 256 + tid;
            int n = it >> 3, g = it & 7;
            const unsigned short* src = xb + cc * CC + n * CIN + ((g ^ (n & 7)) * 8);
            __builtin_amdgcn_global_load_lds(
                (const __attribute__((address_space(1))) void*)src,
                (AS3 void*)(dst + (i * 256 + wv * 64) * 16),
                16, 0, 0);
        }
    };
    unsigned ngoff[AIT], lby[AIT];
#pragma unroll
    for (int i = 0; i < AIT; ++i) {
        int it = i * 256 + tid;
        int n = it >> 3, g = it & 7;
        ngoff[i] = (unsigned)(n * CIN + g * 8);
        lby[i]   = (unsigned)(n * 128 + ((g ^ (n & 7)) << 4));
    }
    auto loadA = [&](int cc, uint4* vv) {
#pragma unroll
        for (int i = 0; i < AIT; ++i)
            vv[i] = *reinterpret_cast<const uint4*>(xb + cc * CC + ngoff[i]);
    };
    const f32x2 iv2 = {inv, inv}, nm2 = {nmi, nmi};
    auto storA = [&](char* wb, const uint4* vv) {
#pragma unroll
        for (int i = 0; i < AIT; ++i) {
            uint4 t = vv[i];
            if (NORM) {
                unsigned int* pw = reinterpret_cast<unsigned int*>(&t);
#pragma unroll
                for (int q = 0; q < 4; ++q) {
                    unsigned int u = pw[q];
                    f32x2 sv, d;
                    sv[0] = __uint_as_float(u << 16);
                    sv[1] = __uint_as_float(u & 0xffff0000u);
                    asm("v_pk_fma_f32 %0, %1, %2, %3" : "=v"(d) : "v"(sv), "v"(iv2), "v"(nm2));
                    float f0 = fmaxf(d[0], 0.f);
                    float f1 = fmaxf(d[1], 0.f);
                    unsigned int r;
                    asm("v_cvt_pk_bf16_f32 %0, %1, %2" : "=v"(r) : "v"(f0), "v"(f1));
                    pw[q] = r;
                }
            }
            *reinterpret_cast<uint4*>(wb + lby[i]) = t;
        }
    };

    // A-read bases (dense rows)
    const int n0 = wm * 64 + l31;
    const int n1 = n0 + 32;
    const unsigned a0b = (unsigned)(n0 * 128), a0x = (unsigned)((n0 & 7) << 4);
    const unsigned a1b = (unsigned)(n1 * 128), a1x = (unsigned)((n1 & 7) << 4);

    uint4 v0[AIT], v1[AIT];

    // prologue: stage chunk 0 (+ prefetch chunk 1's A for NORM path)
    issueB(0, gbuf + ABUF);
    if (GLLA) { issueA(0, gbuf); }
    else {
        loadA(0, v0);
        if (NCC > 1) loadA(1, v1);
        storA(gbuf, v0);
    }
    __syncthreads();

    int p = 0;
#pragma unroll
    for (int cc = 0; cc < NCC; ++cc) {
        if (cc + 1 < NCC) {
            issueB(cc + 1, gbuf + (p ^ 1) * BUFB + ABUF);
            if (GLLA) issueA(cc + 1, gbuf + (p ^ 1) * BUFB);
            else if (cc + 2 < NCC) loadA(cc + 2, (cc & 1) ? v1 : v0);
        }
        const char* ab = gbuf + p * BUFB;
        const char* bb = ab + ABUF;
        __builtin_amdgcn_s_setprio(1);
#pragma unroll
        for (int ks = 0; ks < KS; ++ks) {
            const unsigned so = (unsigned)((ks * 2 + lh2) << 4);
            short8 a0 = *reinterpret_cast<const short8*>(ab + a0b + (so ^ a0x));
            short8 a1 = *reinterpret_cast<const short8*>(ab + a1b + (so ^ a1x));
#pragma unroll
            for (int k = 0; k < 3; ++k) {
                short8 bf_ = *reinterpret_cast<const short8*>(
                    bb + (((k * KS + ks) * 2 + wn) << 10) + lane * 16);
                acc[0][k] = __builtin_amdgcn_mfma_f32_32x32x16_bf16(a0, bf_, acc[0][k], 0, 0, 0);
                acc[1][k] = __builtin_amdgcn_mfma_f32_32x32x16_bf16(a1, bf_, acc[1][k], 0, 0, 0);
            }
        }
        __builtin_amdgcn_s_setprio(0);
        if (!GLLA && cc + 1 < NCC) storA(gbuf + (p ^ 1) * BUFB, (cc & 1) ? v0 : v1);
        __syncthreads();
        p ^= 1;
    }

    // ---------------- epilogue: Z -> LDS (ds_write2, quad-coarse swizzle), gather ----------------
    float* Z = reinterpret_cast<float*>(gbuf);
    float tsum = 0.f, tss = 0.f;
#pragma unroll
    for (int oh = 0; oh < 2; ++oh) {
        if (oh) __syncthreads();
        if (wn == oh) {
#pragma unroll
            for (int k = 0; k < 3; ++k)
#pragma unroll
                for (int nf = 0; nf < 2; ++nf)
#pragma unroll
                    for (int q = 0; q < 4; ++q) {
                        int X = wm * 64 + nf * 32 + 8 * q + 4 * lh2;   // quad base row
                        unsigned zoff = (unsigned)(uintptr_t)(AS3 float*)(
                            Z + ((size_t)(k * NN + X) * 32 + (l31 ^ (X & 28))));
                        asm volatile("ds_write2_b32 %0, %1, %2 offset0:0 offset1:32"
                                     :: "v"(zoff), "v"(acc[nf][k][4 * q + 0]), "v"(acc[nf][k][4 * q + 1]));
                        asm volatile("ds_write2_b32 %0, %1, %2 offset0:64 offset1:96"
                                     :: "v"(zoff), "v"(acc[nf][k][4 * q + 2]), "v"(acc[nf][k][4 * q + 3]));
                    }
        }
        asm volatile("s_waitcnt lgkmcnt(0)" ::: "memory");
        __syncthreads();

        f32x2 val2[8];
        float* vp = reinterpret_cast<float*>(val2);
        {
            const float* bp = bias + oy * 64 + oh * 32 + eh * 16;
#pragma unroll
            for (int j = 0; j < 16; ++j) vp[j] = bp[j];
        }
#pragma unroll
        for (int k = 0; k < 3; ++k) {
            const float* zr = Z + (k * NN + sk[k]) * 32;
            const int sw = (sk[k] >> 2) & 7;
#pragma unroll
            for (int q4 = 0; q4 < 4; ++q4) {
                const int q = eh * 4 + q4;
                float4 z = *reinterpret_cast<const float4*>(zr + ((q ^ sw) << 2));
                f32x2 zlo = {z.x, z.y}, zhi = {z.z, z.w};
                val2[q4 * 2 + 0] += zlo;
                val2[q4 * 2 + 1] += zhi;
            }
        }
#pragma unroll
        for (int j = 0; j < 16; ++j) { tsum += vp[j]; tss += vp[j] * vp[j]; }

        if (COLMAX) {
#pragma unroll
            for (int m = 2; m <= 32; m <<= 1)
#pragma unroll
                for (int j = 0; j < 16; ++j) vp[j] = fmaxf(vp[j], __shfl_xor(vp[j], m));
            if ((lane >> 1) == 0) {
#pragma unroll
                for (int j = 0; j < 16; ++j) cmax[wv][lane & 1][j] = vp[j];
            }
            __syncthreads();
            if (tid < 32) {
                float m = fmaxf(fmaxf(cmax[0][tid >> 4][tid & 15], cmax[1][tid >> 4][tid & 15]),
                                fmaxf(cmax[2][tid >> 4][tid & 15], cmax[3][tid >> 4][tid & 15]));
                colmax[b * COUT + oy * 64 + oh * 32 + tid] = m;
            }
        } else {
            unsigned int pk[8];
#pragma unroll
            for (int j = 0; j < 8; ++j)
                asm("v_cvt_pk_bf16_f32 %0, %1, %2" : "=v"(pk[j]) : "v"(vp[2 * j]), "v"(vp[2 * j + 1]));
            unsigned short* dst = yout + ((size_t)b * NN + en) * COUT + oy * 64 + oh * 32 + eh * 16;
            reinterpret_cast<uint4*>(dst)[0] = make_uint4(pk[0], pk[1], pk[2], pk[3]);
            reinterpret_cast<uint4*>(dst)[1] = make_uint4(pk[4], pk[5], pk[6], pk[7]);
        }
    }

    // block stats reduction
#pragma unroll
    for (int ss = 32; ss; ss >>= 1) { tsum += __shfl_down(tsum, ss); tss += __shfl_down(tss, ss); }
    if (lane == 0) { rbuf[wv * 2] = tsum; rbuf[wv * 2 + 1] = tss; }
    __syncthreads();
    if (tid == 0) {
        float sm = rbuf[0] + rbuf[2] + rbuf[4] + rbuf[6];
        float q = rbuf[1] + rbuf[3] + rbuf[5] + rbuf[7];
        int gid = oy * B + b;
        partials[2 * gid] = sm;
        partials[2 * gid + 1] = q;
    }
}

// ---------- finalize global layernorm stats ----------
__global__ __launch_bounds__(256) void stats_kernel(const float* __restrict__ partials,
                                                    float* __restrict__ stats,
                                                    int npart, double ntot)
{
    __shared__ double sd[256], sd2[256];
    double s = 0.0, s2 = 0.0;
    for (int i = threadIdx.x; i < npart; i += 256) { s += (double)partials[2 * i]; s2 += (double)partials[2 * i + 1]; }
    sd[threadIdx.x] = s; sd2[threadIdx.x] = s2;
    __syncthreads();
    for (int k = 128; k > 0; k >>= 1) {
        if (threadIdx.x < k) { sd[threadIdx.x] += sd[threadIdx.x + k]; sd2[threadIdx.x] += sd2[threadIdx.x + k]; }
        __syncthreads();
    }
    if (threadIdx.x == 0) {
        double mu = sd[0] / ntot;
        double var = (sd2[0] - sd[0] * sd[0] / ntot) / (ntot - 1.0);
        double sdv = sqrt(var > 0.0 ? var : 0.0);
        stats[0] = (float)mu;
        stats[1] = (float)(1.0 / (sdv + 1e-5));
    }
}

// ---------- heads from per-column max (raw) ----------
__global__ __launch_bounds__(128) void pool_head_kernel(const float* __restrict__ colmax,  // [B][128]
                                                        const float* __restrict__ stats,
                                                        const float* __restrict__ latw,
                                                        const float* __restrict__ latb,
                                                        const float* __restrict__ costw,
                                                        const float* __restrict__ costb,
                                                        float* __restrict__ out)
{
    const int b = blockIdx.x, t = threadIdx.x;
    const float mu = stats[0], inv = stats[1];
    const float pooled = fmaxf((colmax[b * 128 + t] - mu) * inv, 0.f);
    __shared__ float pl[128];
    pl[t] = pooled;
    __syncthreads();
    const float* w = (t < 64) ? latw : costw;
    const int l = t & 63;
    float v = pl[l] * w[l] + pl[l + 64] * w[l + 64];
#pragma unroll
    for (int s = 32; s > 0; s >>= 1) v += __shfl_down(v, s);
    if (l == 0) {
        const float bb = (t < 64) ? latb[0] : costb[0];
        out[(t < 64 ? 0 : B) + b] = 1.f / (1.f + expf(-(v + bb)));
    }
}

// ---------- launch ----------
extern "C" void kernel_launch(void* const* d_in, const int* in_sizes, int n_in,
                              void* d_out, int out_size, void* d_ws, size_t ws_size,
                              hipStream_t stream)
{
    (void)in_sizes; (void)n_in; (void)out_size; (void)ws_size;
    const float* trees   = (const float*)d_in[0];
    const int*   indexes = (const int*)  d_in[1];
    const float* enc_w   = (const float*)d_in[2];
    const float* enc_b   = (const float*)d_in[3];
    const float* w1 = (const float*)d_in[4];
    const float* b1 = (const float*)d_in[5];
    const float* w2 = (const float*)d_in[6];
    const float* b2 = (const float*)d_in[7];
    const float* w3 = (const float*)d_in[8];
    const float* b3 = (const float*)d_in[9];
    const float* lat_w  = (const float*)d_in[10];
    const float* lat_b  = (const float*)d_in[11];
    const float* cost_w = (const float*)d_in[12];
    const float* cost_b = (const float*)d_in[13];
    float* out = (float*)d_out;

    char* ws = (char*)d_ws;
    size_t off = 0;
    auto alloc = [&](size_t bytes) -> char* {
        char* p = ws + off;
        off += (bytes + 255) & ~(size_t)255;
        return p;
    };
    unsigned short* wpe = (unsigned short*)alloc((size_t)320 * 128 * 2);
    unsigned short* wp1 = (unsigned short*)alloc((size_t)3 * 128 * 512 * 2);
    unsigned short* wp2 = (unsigned short*)alloc((size_t)3 * 512 * 256 * 2);
    unsigned short* wp3 = (unsigned short*)alloc((size_t)3 * 256 * 128 * 2);
    unsigned short* x0  = (unsigned short*)alloc((size_t)B * NN * 128 * 2);
    unsigned short* y1  = (unsigned short*)alloc((size_t)B * NN * 512 * 2);
    unsigned short* y2  = (unsigned short*)alloc((size_t)B * NN * 256 * 2);
    float* colmax   = (float*)alloc((size_t)B * 128 * 4);
    float* partials = (float*)alloc((size_t)8192 * 2 * 4);
    float* stats    = (float*)alloc(8 * 4);

    prepack_w32<<<dim3((320 * 128 + 255) / 256), dim3(256), 0, stream>>>(enc_w, wpe, 1, 109, 318, 64, 128, 4, 5, 320);
    prepack_wB<<<dim3((3 * 128 * 512) / 256), dim3(256), 0, stream>>>(w1, wp1, 512, 109, 128, 512);
    prepack_wB<<<dim3((3 * 512 * 256) / 256), dim3(256), 0, stream>>>(w2, wp2, 256, 512, 512, 256);
    prepack_wB<<<dim3((3 * 256 * 128) / 256), dim3(256), 0, stream>>>(w3, wp3, 128, 256, 256, 128);

    // encoder (fused transpose): trees -> x0 [B][NN][128]
    enc_fused<<<dim3(B), dim3(256), 0, stream>>>(trees, wpe, enc_b, x0);

    // conv1: all-LDS operands, full GLL staging (NCC=2)
    conv_gemm<128, 8, 512, false, false, true>
        <<<dim3(B * 8), dim3(256), 0, stream>>>(x0, indexes, wp1, b1, stats, y1, colmax, partials);
    stats_kernel<<<dim3(1), dim3(256), 0, stream>>>(partials, stats + 0, 8192, (double)((size_t)B * 512 * NN));

    // conv2: B via GLL, A via VGPR+norm transform, 2-deep A prefetch (NCC=8)
    conv_gemm<512, 4, 256, true, false, false>
        <<<dim3(B * 4), dim3(256), 0, stream>>>(y1, indexes, wp2, b2, stats + 0, y2, colmax, partials);
    stats_kernel<<<dim3(1), dim3(256), 0, stream>>>(partials, stats + 2, 4096, (double)((size_t)B * 256 * NN));

    // conv3: per-column raw max (pool fused, NCC=4)
    conv_gemm<256, 2, 128, true, true, false>
        <<<dim3(B * 2), dim3(256), 0, stream>>>(y2, indexes, wp3, b3, stats + 2, nullptr, colmax, partials);
    stats_kernel<<<dim3(1), dim3(256), 0, stream>>>(partials, stats + 4, 2048, (double)((size_t)B * 128 * NN));

    pool_head_kernel<<<dim3(B), dim3(128), 0, stream>>>(colmax, stats + 4, lat_w, lat_b, cost_w, cost_b, out);
}